// Round 2
// baseline (1142.253 us; speedup 1.0000x reference)
//
#include <hip/hip_runtime.h>
#include <math.h>

// Problem constants (fixed by the reference)
#define Nn 100000
#define Ee 1600000
#define Gg 2048
#define HH 128
#define BN_EPS 1e-5f

// ---------------------------------------------------------------------------
// Degree count (dst side), dis = rsqrt(deg+1)
// ---------------------------------------------------------------------------
__global__ __launch_bounds__(256) void k_count(const int* __restrict__ dst,
                                               unsigned* __restrict__ cnt) {
    int e = blockIdx.x * 256 + threadIdx.x;
    if (e < Ee) atomicAdd(&cnt[dst[e]], 1u);
}

__global__ __launch_bounds__(256) void k_dis(const unsigned* __restrict__ cnt,
                                             float* __restrict__ dis) {
    int i = blockIdx.x * 256 + threadIdx.x;
    if (i < Nn) dis[i] = rsqrtf((float)cnt[i] + 1.0f);
}

// ---------------------------------------------------------------------------
// Exclusive prefix scan of cnt -> rowptr (3 kernels). 391 blocks of 256.
// ---------------------------------------------------------------------------
__global__ __launch_bounds__(256) void k_scan1(const unsigned* __restrict__ cnt,
                                               int* __restrict__ rowptr,
                                               int* __restrict__ bsum) {
    __shared__ int tmp[256];
    int t = threadIdx.x;
    int i = blockIdx.x * 256 + t;
    int v = (i < Nn) ? (int)cnt[i] : 0;
    tmp[t] = v;
    __syncthreads();
    for (int off = 1; off < 256; off <<= 1) {
        int u = (t >= off) ? tmp[t - off] : 0;
        __syncthreads();
        tmp[t] += u;
        __syncthreads();
    }
    if (i < Nn) rowptr[i] = tmp[t] - v;          // exclusive within block
    if (t == 255) bsum[blockIdx.x] = tmp[t];     // block total
}

__global__ void k_scan2(int* __restrict__ bsum, int nb) {
    __shared__ int tmp[512];
    int t = threadIdx.x;
    int v = (t < nb) ? bsum[t] : 0;
    tmp[t] = v;
    __syncthreads();
    for (int off = 1; off < 512; off <<= 1) {
        int u = (t >= off) ? tmp[t - off] : 0;
        __syncthreads();
        tmp[t] += u;
        __syncthreads();
    }
    if (t < nb) bsum[t] = tmp[t] - v;            // exclusive block offsets
}

__global__ __launch_bounds__(256) void k_scan3(int* __restrict__ rowptr,
                                               int* __restrict__ cursor,
                                               const int* __restrict__ bsum) {
    int i = blockIdx.x * 256 + threadIdx.x;
    if (i < Nn) {
        int r = rowptr[i] + bsum[blockIdx.x];
        rowptr[i] = r;
        cursor[i] = r;
    }
    if (i == 0) rowptr[Nn] = Ee;
}

// ---------------------------------------------------------------------------
// CSR fill: bucket edges by dst via atomic cursor; precompute edge norm.
// ---------------------------------------------------------------------------
__global__ __launch_bounds__(256) void k_fill(const int* __restrict__ src,
                                              const int* __restrict__ dst,
                                              const float* __restrict__ dis,
                                              int* __restrict__ cursor,
                                              int* __restrict__ csr_src,
                                              float* __restrict__ csr_w) {
    int e = blockIdx.x * 256 + threadIdx.x;
    if (e < Ee) {
        int s = src[e], d = dst[e];
        int pos = atomicAdd(&cursor[d], 1);
        csr_src[pos] = s;
        csr_w[pos]   = dis[s] * dis[d];
    }
}

// ---------------------------------------------------------------------------
// GEMM: XW = X @ W + b.  X:[N,128] W:[128,128] (k-major) b:[128]
// Block 256 threads. blockIdx&1 selects feature half (64 cols).
// LDS: Ws[64][132] transposed (f-major, k contiguous -> ds_read_b128),
//      Xs[32][132]. Per-thread acc[2 rows][4 feats].
// ---------------------------------------------------------------------------
__global__ __launch_bounds__(256) void k_gemm(const float* __restrict__ X,
                                              const float* __restrict__ W,
                                              const float* __restrict__ Bv,
                                              float* __restrict__ XW) {
    __shared__ float Ws[64 * 132];
    __shared__ float Xs[32 * 132];
    const int tid = threadIdx.x;
    const int fhalf = blockIdx.x & 1;

    // Stage W half, transposed: Ws[f][k] = W[k][fhalf*64+f]
    {
        int f = tid & 63;
        int krow = tid >> 6;  // 0..3
#pragma unroll
        for (int it = 0; it < 32; ++it) {
            int k = krow + it * 4;
            Ws[f * 132 + k] = W[k * 128 + fhalf * 64 + f];
        }
    }
    const int fg = tid & 15;   // feature group: f = fhalf*64 + fg + j*16
    const int rg = tid >> 4;   // row group: rows rg*2, rg*2+1 of tile
    float bias[4];
#pragma unroll
    for (int j = 0; j < 4; ++j) bias[j] = Bv[fhalf * 64 + fg + j * 16];

    const int ntiles = Nn / 32;  // 3125, exact
    for (int t = (int)(blockIdx.x >> 1); t < ntiles; t += (int)(gridDim.x >> 1)) {
        __syncthreads();  // Xs from previous iter consumed; Ws ready (iter 0)
        {
            int r = tid >> 3;  // 0..31
            int c = tid & 7;
            const float4* Xr = (const float4*)(X + (size_t)(t * 32 + r) * 128);
#pragma unroll
            for (int it = 0; it < 4; ++it) {
                float4 v = Xr[c + it * 8];
                *(float4*)&Xs[r * 132 + (c + it * 8) * 4] = v;
            }
        }
        __syncthreads();

        float acc[2][4];
#pragma unroll
        for (int r = 0; r < 2; ++r)
#pragma unroll
            for (int j = 0; j < 4; ++j) acc[r][j] = bias[j];

#pragma unroll 8
        for (int k = 0; k < 128; k += 4) {
            float4 x0 = *(const float4*)&Xs[(rg * 2 + 0) * 132 + k];
            float4 x1 = *(const float4*)&Xs[(rg * 2 + 1) * 132 + k];
#pragma unroll
            for (int j = 0; j < 4; ++j) {
                float4 w = *(const float4*)&Ws[(fg + j * 16) * 132 + k];
                acc[0][j] += x0.x * w.x + x0.y * w.y + x0.z * w.z + x0.w * w.w;
                acc[1][j] += x1.x * w.x + x1.y * w.y + x1.z * w.z + x1.w * w.w;
            }
        }
        int rowb = t * 32 + rg * 2;
#pragma unroll
        for (int r = 0; r < 2; ++r) {
            float* o = XW + (size_t)(rowb + r) * 128 + fhalf * 64 + fg;
            o[0]  = acc[r][0];
            o[16] = acc[r][1];
            o[32] = acc[r][2];
            o[48] = acc[r][3];
        }
    }
}

// ---------------------------------------------------------------------------
// Aggregate: HP[i] = sum_{e: dst=i} XW[src_e]*w_e + XW[i]*dis[i]^2
// One wave per node, float2 per lane (128 feats / 64 lanes).
// ---------------------------------------------------------------------------
__global__ __launch_bounds__(256) void k_agg(const float* __restrict__ XW,
                                             const float* __restrict__ dis,
                                             const int* __restrict__ rowptr,
                                             const int* __restrict__ csr_src,
                                             const float* __restrict__ csr_w,
                                             float* __restrict__ HP) {
    int node = blockIdx.x * 4 + (threadIdx.x >> 6);  // 25000*4 = 100000 exact
    int l = threadIdx.x & 63;
    const float2* XW2 = (const float2*)XW;
    int beg = rowptr[node], end = rowptr[node + 1];
    float ax = 0.f, ay = 0.f;
    for (int j = beg; j < end; ++j) {
        int s   = csr_src[j];
        float w = csr_w[j];
        float2 v = XW2[(size_t)s * 64 + l];
        ax = fmaf(w, v.x, ax);
        ay = fmaf(w, v.y, ay);
    }
    float d = dis[node];
    float d2 = d * d;
    float2 vs = XW2[(size_t)node * 64 + l];
    ax = fmaf(d2, vs.x, ax);
    ay = fmaf(d2, vs.y, ay);
    float2 r; r.x = ax; r.y = ay;
    ((float2*)HP)[(size_t)node * 64 + l] = r;
}

// ---------------------------------------------------------------------------
// BN stats: per-feature sum and sum-of-squares over N rows.
// ---------------------------------------------------------------------------
__global__ __launch_bounds__(256) void k_stats(const float* __restrict__ HP,
                                               float* __restrict__ stats) {
    int f = threadIdx.x & 127;
    int half = threadIdx.x >> 7;
    float s = 0.f, sq = 0.f;
    for (int r = blockIdx.x * 2 + half; r < Nn; r += gridDim.x * 2) {
        float v = HP[(size_t)r * 128 + f];
        s += v;
        sq = fmaf(v, v, sq);
    }
    __shared__ float ls[256], lq[256];
    ls[threadIdx.x] = s;
    lq[threadIdx.x] = sq;
    __syncthreads();
    if (threadIdx.x < 128) {
        s  = ls[threadIdx.x] + ls[threadIdx.x + 128];
        sq = lq[threadIdx.x] + lq[threadIdx.x + 128];
        atomicAdd(&stats[f], s);
        atomicAdd(&stats[128 + f], sq);
    }
}

__global__ void k_bnfinal(const float* __restrict__ stats,
                          const float* __restrict__ g,
                          const float* __restrict__ bt,
                          float* __restrict__ bnp) {
    int f = threadIdx.x;  // 128 threads
    float mu  = stats[f] * (1.0f / Nn);
    float var = stats[128 + f] * (1.0f / Nn) - mu * mu;
    float sc  = g[f] * rsqrtf(var + BN_EPS);
    bnp[f]       = sc;
    bnp[128 + f] = bt[f] - mu * sc;
}

// h = relu(HP*scale + shift), float4-vectorized
__global__ __launch_bounds__(256) void k_norm(const float* __restrict__ HP,
                                              const float* __restrict__ bnp,
                                              float* __restrict__ Ho) {
    const float4* hp4 = (const float4*)HP;
    float4* ho4 = (float4*)Ho;
    const float4* sc4 = (const float4*)bnp;
    const float4* sh4 = (const float4*)(bnp + 128);
    int stride = gridDim.x * blockDim.x;
    for (int i = blockIdx.x * blockDim.x + threadIdx.x; i < Nn * 32; i += stride) {
        int f4 = i & 31;
        float4 v = hp4[i];
        float4 sc = sc4[f4], sh = sh4[f4];
        float4 o;
        o.x = fmaxf(fmaf(v.x, sc.x, sh.x), 0.f);
        o.y = fmaxf(fmaf(v.y, sc.y, sh.y), 0.f);
        o.z = fmaxf(fmaf(v.z, sc.z, sh.z), 0.f);
        o.w = fmaxf(fmaf(v.w, sc.w, sh.w), 0.f);
        ho4[i] = o;
    }
}

// ---------------------------------------------------------------------------
// Fused mean-pool + FC1(relu) + FC2. One block (128 thr) per graph.
// batch is sorted -> binary search the node range.
// ---------------------------------------------------------------------------
__global__ __launch_bounds__(128) void k_pool_fc(const float* __restrict__ Hf,
                                                 const int* __restrict__ batch,
                                                 const float* __restrict__ fcw1,
                                                 const float* __restrict__ fcb1,
                                                 const float* __restrict__ fcw2,
                                                 const float* __restrict__ fcb2,
                                                 float* __restrict__ out) {
    int g = blockIdx.x;
    int t = threadIdx.x;
    int lo = 0, hi = Nn;
    while (lo < hi) { int mid = (lo + hi) >> 1; if (batch[mid] < g) lo = mid + 1; else hi = mid; }
    int start = lo;
    hi = Nn;
    while (lo < hi) { int mid = (lo + hi) >> 1; if (batch[mid] < g + 1) lo = mid + 1; else hi = mid; }
    int end = lo;

    float acc = 0.f;
    for (int i = start; i < end; ++i) acc += Hf[(size_t)i * 128 + t];
    float inv = 1.0f / fmaxf((float)(end - start), 1.0f);

    __shared__ float p[128];
    __shared__ float h1[64];
    p[t] = acc * inv;
    __syncthreads();
    if (t < 64) {
        float s = fcb1[t];
        for (int k = 0; k < 128; ++k) s = fmaf(p[k], fcw1[k * 64 + t], s);
        h1[t] = fmaxf(s, 0.f);
    }
    __syncthreads();
    if (t < 64) {
        float v = h1[t] * fcw2[t];
        for (int off = 32; off > 0; off >>= 1) v += __shfl_down(v, off, 64);
        if (t == 0) out[g] = v + fcb2[0];
    }
}

// ---------------------------------------------------------------------------
extern "C" void kernel_launch(void* const* d_in, const int* in_sizes, int n_in,
                              void* d_out, int out_size, void* d_ws, size_t ws_size,
                              hipStream_t stream) {
    const float* x     = (const float*)d_in[0];
    const int*   ei    = (const int*)d_in[1];   // [2,E]: src=ei[0:E), dst=ei[E:2E)
    const int*   batch = (const int*)d_in[2];
    const float* W1  = (const float*)d_in[3];
    const float* b1  = (const float*)d_in[4];
    const float* g1  = (const float*)d_in[5];
    const float* bt1 = (const float*)d_in[6];
    const float* W2  = (const float*)d_in[7];
    const float* b2  = (const float*)d_in[8];
    const float* g2  = (const float*)d_in[9];
    const float* bt2 = (const float*)d_in[10];
    const float* W3  = (const float*)d_in[11];
    const float* b3  = (const float*)d_in[12];
    const float* g3  = (const float*)d_in[13];
    const float* bt3 = (const float*)d_in[14];
    const float* fcw1 = (const float*)d_in[15];
    const float* fcb1 = (const float*)d_in[16];
    const float* fcw2 = (const float*)d_in[17];
    const float* fcb2 = (const float*)d_in[18];
    float* out = (float*)d_out;

    // Workspace layout (~168 MB total)
    float*    ws0     = (float*)d_ws;            // XW      [N*128]
    float*    ws1     = ws0 + (size_t)Nn * HH;   // HP      [N*128]
    float*    ws2     = ws1 + (size_t)Nn * HH;   // h       [N*128]
    float*    dis     = ws2 + (size_t)Nn * HH;   // [N]
    unsigned* cnt     = (unsigned*)(dis + Nn);   // [N]
    int*      rowptr  = (int*)(cnt + Nn);        // [N+1]
    int*      cursor  = rowptr + (Nn + 1);       // [N+1]
    int*      bsum    = cursor + (Nn + 1);       // [512]
    int*      csr_src = bsum + 512;              // [E]
    float*    csr_w   = (float*)(csr_src + Ee);  // [E]
    float*    stats   = csr_w + Ee;              // [3*256]
    float*    bnp     = stats + 768;             // [256]

    hipMemsetAsync(cnt, 0, (size_t)Nn * sizeof(unsigned), stream);
    hipMemsetAsync(stats, 0, 768 * sizeof(float), stream);

    const int* src = ei;
    const int* dst = ei + Ee;

    k_count<<<Ee / 256, 256, 0, stream>>>(dst, cnt);
    k_dis<<<(Nn + 255) / 256, 256, 0, stream>>>(cnt, dis);
    int nblk = (Nn + 255) / 256;  // 391
    k_scan1<<<nblk, 256, 0, stream>>>(cnt, rowptr, bsum);
    k_scan2<<<1, 512, 0, stream>>>(bsum, nblk);
    k_scan3<<<nblk, 256, 0, stream>>>(rowptr, cursor, bsum);
    k_fill<<<Ee / 256, 256, 0, stream>>>(src, dst, dis, cursor, csr_src, csr_w);

    const float* Ws_[3]  = {W1, W2, W3};
    const float* bs_[3]  = {b1, b2, b3};
    const float* gs_[3]  = {g1, g2, g3};
    const float* bts_[3] = {bt1, bt2, bt3};
    const float* Xin = x;
    for (int l = 0; l < 3; ++l) {
        k_gemm<<<768, 256, 0, stream>>>(Xin, Ws_[l], bs_[l], ws0);
        k_agg<<<Nn / 4, 256, 0, stream>>>(ws0, dis, rowptr, csr_src, csr_w, ws1);
        k_stats<<<1024, 256, 0, stream>>>(ws1, stats + l * 256);
        k_bnfinal<<<1, 128, 0, stream>>>(stats + l * 256, gs_[l], bts_[l], bnp);
        k_norm<<<2048, 256, 0, stream>>>(ws1, bnp, ws2);
        Xin = ws2;
    }
    k_pool_fc<<<Gg, 128, 0, stream>>>(ws2, batch, fcw1, fcb1, fcw2, fcb2, out);
}

// Round 3
// 840.861 us; speedup vs baseline: 1.3584x; 1.3584x over previous
//
#include <hip/hip_runtime.h>
#include <math.h>

// Problem constants (fixed by the reference)
#define Nn 100000
#define Ee 1600000
#define Gg 2048
#define HH 128
#define BN_EPS 1e-5f

typedef unsigned int uint32;
typedef unsigned short ushort16;

__device__ __forceinline__ ushort16 f2bf(float f) {
    union { float f; uint32 u; } c; c.f = f;
    uint32 r = (c.u + 0x7FFFu + ((c.u >> 16) & 1u)) >> 16;   // RTNE
    return (ushort16)r;
}
__device__ __forceinline__ float bflo(uint32 v) {
    union { uint32 u; float f; } c; c.u = v << 16; return c.f;
}
__device__ __forceinline__ float bfhi(uint32 v) {
    union { uint32 u; float f; } c; c.u = v & 0xFFFF0000u; return c.f;
}

// ---------------------------------------------------------------------------
// Degree count (dst side), dis = rsqrt(deg+1)
// ---------------------------------------------------------------------------
__global__ __launch_bounds__(256) void k_count(const int* __restrict__ dst,
                                               unsigned* __restrict__ cnt) {
    int e = blockIdx.x * 256 + threadIdx.x;
    if (e < Ee) atomicAdd(&cnt[dst[e]], 1u);
}

__global__ __launch_bounds__(256) void k_dis(const unsigned* __restrict__ cnt,
                                             float* __restrict__ dis) {
    int i = blockIdx.x * 256 + threadIdx.x;
    if (i < Nn) dis[i] = rsqrtf((float)cnt[i] + 1.0f);
}

// ---------------------------------------------------------------------------
// Exclusive prefix scan of cnt -> rowptr (3 kernels). 391 blocks of 256.
// ---------------------------------------------------------------------------
__global__ __launch_bounds__(256) void k_scan1(const unsigned* __restrict__ cnt,
                                               int* __restrict__ rowptr,
                                               int* __restrict__ bsum) {
    __shared__ int tmp[256];
    int t = threadIdx.x;
    int i = blockIdx.x * 256 + t;
    int v = (i < Nn) ? (int)cnt[i] : 0;
    tmp[t] = v;
    __syncthreads();
    for (int off = 1; off < 256; off <<= 1) {
        int u = (t >= off) ? tmp[t - off] : 0;
        __syncthreads();
        tmp[t] += u;
        __syncthreads();
    }
    if (i < Nn) rowptr[i] = tmp[t] - v;          // exclusive within block
    if (t == 255) bsum[blockIdx.x] = tmp[t];     // block total
}

__global__ void k_scan2(int* __restrict__ bsum, int nb) {
    __shared__ int tmp[512];
    int t = threadIdx.x;
    int v = (t < nb) ? bsum[t] : 0;
    tmp[t] = v;
    __syncthreads();
    for (int off = 1; off < 512; off <<= 1) {
        int u = (t >= off) ? tmp[t - off] : 0;
        __syncthreads();
        tmp[t] += u;
        __syncthreads();
    }
    if (t < nb) bsum[t] = tmp[t] - v;            // exclusive block offsets
}

__global__ __launch_bounds__(256) void k_scan3(int* __restrict__ rowptr,
                                               int* __restrict__ cursor,
                                               const int* __restrict__ bsum) {
    int i = blockIdx.x * 256 + threadIdx.x;
    if (i < Nn) {
        int r = rowptr[i] + bsum[blockIdx.x];
        rowptr[i] = r;
        cursor[i] = r;
    }
    if (i == 0) rowptr[Nn] = Ee;
}

// ---------------------------------------------------------------------------
// CSR fill: bucket edges by dst via atomic cursor. No weights needed:
// HP[i] = dis[i] * (sum_src XW'[src] + XW'[i]) with XW' = dis*xw pre-scaled.
// ---------------------------------------------------------------------------
__global__ __launch_bounds__(256) void k_fill(const int* __restrict__ src,
                                              const int* __restrict__ dst,
                                              int* __restrict__ cursor,
                                              int* __restrict__ csr_src) {
    int e = blockIdx.x * 256 + threadIdx.x;
    if (e < Ee) {
        int s = src[e], d = dst[e];
        int pos = atomicAdd(&cursor[d], 1);
        csr_src[pos] = s;
    }
}

// ---------------------------------------------------------------------------
// GEMM: XW' = dis * (Xin @ W + b), output bf16.
// Xin = raw floats (bnp==null) or relu(HP*sc+sh) applied on LDS staging.
// Block 256 threads; blockIdx&1 selects feature half (64 cols).
// ---------------------------------------------------------------------------
__global__ __launch_bounds__(256) void k_gemm(const float* __restrict__ X,
                                              const float* __restrict__ W,
                                              const float* __restrict__ Bv,
                                              const float* __restrict__ bnp,
                                              const float* __restrict__ dis,
                                              ushort16* __restrict__ XWb) {
    __shared__ float Ws[64 * 132];
    __shared__ float Xs[32 * 132];
    const int tid = threadIdx.x;
    const int fhalf = blockIdx.x & 1;

    // Stage W half, transposed: Ws[f][k] = W[k][fhalf*64+f]
    {
        int f = tid & 63;
        int krow = tid >> 6;  // 0..3
#pragma unroll
        for (int it = 0; it < 32; ++it) {
            int k = krow + it * 4;
            Ws[f * 132 + k] = W[k * 128 + fhalf * 64 + f];
        }
    }
    // BN params for this thread's staging columns (fixed across tiles)
    const int lc = tid & 7;  // staging column group
    float4 scv[4], shv[4];
    if (bnp) {
        const float4* sc4 = (const float4*)bnp;
        const float4* sh4 = (const float4*)(bnp + 128);
#pragma unroll
        for (int it = 0; it < 4; ++it) {
            scv[it] = sc4[lc + it * 8];
            shv[it] = sh4[lc + it * 8];
        }
    }
    const int fg = tid & 15;   // feature: f = fhalf*64 + fg + j*16
    const int rg = tid >> 4;   // rows rg*2, rg*2+1 of tile
    float bias[4];
#pragma unroll
    for (int j = 0; j < 4; ++j) bias[j] = Bv[fhalf * 64 + fg + j * 16];

    const int ntiles = Nn / 32;  // 3125, exact
    for (int t = (int)(blockIdx.x >> 1); t < ntiles; t += (int)(gridDim.x >> 1)) {
        __syncthreads();
        {
            int r = tid >> 3;  // 0..31
            const float4* Xr = (const float4*)(X + (size_t)(t * 32 + r) * 128);
#pragma unroll
            for (int it = 0; it < 4; ++it) {
                float4 v = Xr[lc + it * 8];
                if (bnp) {
                    v.x = fmaxf(fmaf(v.x, scv[it].x, shv[it].x), 0.f);
                    v.y = fmaxf(fmaf(v.y, scv[it].y, shv[it].y), 0.f);
                    v.z = fmaxf(fmaf(v.z, scv[it].z, shv[it].z), 0.f);
                    v.w = fmaxf(fmaf(v.w, scv[it].w, shv[it].w), 0.f);
                }
                *(float4*)&Xs[r * 132 + (lc + it * 8) * 4] = v;
            }
        }
        __syncthreads();

        float acc[2][4];
#pragma unroll
        for (int r = 0; r < 2; ++r)
#pragma unroll
            for (int j = 0; j < 4; ++j) acc[r][j] = bias[j];

#pragma unroll 8
        for (int k = 0; k < 128; k += 4) {
            float4 x0 = *(const float4*)&Xs[(rg * 2 + 0) * 132 + k];
            float4 x1 = *(const float4*)&Xs[(rg * 2 + 1) * 132 + k];
#pragma unroll
            for (int j = 0; j < 4; ++j) {
                float4 w = *(const float4*)&Ws[(fg + j * 16) * 132 + k];
                acc[0][j] += x0.x * w.x + x0.y * w.y + x0.z * w.z + x0.w * w.w;
                acc[1][j] += x1.x * w.x + x1.y * w.y + x1.z * w.z + x1.w * w.w;
            }
        }
        int rowb = t * 32 + rg * 2;
#pragma unroll
        for (int r = 0; r < 2; ++r) {
            float dsc = dis[rowb + r];
            ushort16* o = XWb + (size_t)(rowb + r) * 128 + fhalf * 64 + fg;
            o[0]  = f2bf(acc[r][0] * dsc);
            o[16] = f2bf(acc[r][1] * dsc);
            o[32] = f2bf(acc[r][2] * dsc);
            o[48] = f2bf(acc[r][3] * dsc);
        }
    }
}

// ---------------------------------------------------------------------------
// Aggregate: HP[i] = dis[i] * (sum_{e:dst=i} XW'[src_e] + XW'[i])
// One wave per node; lane holds 2 features (one packed bf16x2 word).
// Edge loop unrolled x4 for memory-level parallelism.
// ---------------------------------------------------------------------------
__global__ __launch_bounds__(256) void k_agg(const ushort16* __restrict__ XWb,
                                             const float* __restrict__ dis,
                                             const int* __restrict__ rowptr,
                                             const int* __restrict__ csr_src,
                                             float* __restrict__ HP) {
    int node = blockIdx.x * 4 + (threadIdx.x >> 6);  // 25000*4 = 100000 exact
    int l = threadIdx.x & 63;
    const uint32* XW32 = (const uint32*)XWb;         // [N][64] packed bf16x2
    int beg = rowptr[node], end = rowptr[node + 1];
    float ax = 0.f, ay = 0.f;
    int j = beg;
    for (; j + 4 <= end; j += 4) {
        int s0 = csr_src[j + 0];
        int s1 = csr_src[j + 1];
        int s2 = csr_src[j + 2];
        int s3 = csr_src[j + 3];
        uint32 v0 = XW32[(size_t)s0 * 64 + l];
        uint32 v1 = XW32[(size_t)s1 * 64 + l];
        uint32 v2 = XW32[(size_t)s2 * 64 + l];
        uint32 v3 = XW32[(size_t)s3 * 64 + l];
        ax += bflo(v0); ay += bfhi(v0);
        ax += bflo(v1); ay += bfhi(v1);
        ax += bflo(v2); ay += bfhi(v2);
        ax += bflo(v3); ay += bfhi(v3);
    }
    for (; j < end; ++j) {
        int s = csr_src[j];
        uint32 v = XW32[(size_t)s * 64 + l];
        ax += bflo(v); ay += bfhi(v);
    }
    uint32 vs = XW32[(size_t)node * 64 + l];
    ax += bflo(vs); ay += bfhi(vs);
    float d = dis[node];
    float2 r; r.x = ax * d; r.y = ay * d;
    ((float2*)HP)[(size_t)node * 64 + l] = r;
}

// ---------------------------------------------------------------------------
// BN stats: per-feature sum and sum-of-squares over N rows.
// ---------------------------------------------------------------------------
__global__ __launch_bounds__(256) void k_stats(const float* __restrict__ HP,
                                               float* __restrict__ stats) {
    int f = threadIdx.x & 127;
    int half = threadIdx.x >> 7;
    float s = 0.f, sq = 0.f;
    for (int r = blockIdx.x * 2 + half; r < Nn; r += gridDim.x * 2) {
        float v = HP[(size_t)r * 128 + f];
        s += v;
        sq = fmaf(v, v, sq);
    }
    __shared__ float ls[256], lq[256];
    ls[threadIdx.x] = s;
    lq[threadIdx.x] = sq;
    __syncthreads();
    if (threadIdx.x < 128) {
        s  = ls[threadIdx.x] + ls[threadIdx.x + 128];
        sq = lq[threadIdx.x] + lq[threadIdx.x + 128];
        atomicAdd(&stats[f], s);
        atomicAdd(&stats[128 + f], sq);
    }
}

__global__ void k_bnfinal(const float* __restrict__ stats,
                          const float* __restrict__ g,
                          const float* __restrict__ bt,
                          float* __restrict__ bnp) {
    int f = threadIdx.x;  // 128 threads
    float mu  = stats[f] * (1.0f / Nn);
    float var = stats[128 + f] * (1.0f / Nn) - mu * mu;
    float sc  = g[f] * rsqrtf(var + BN_EPS);
    bnp[f]       = sc;
    bnp[128 + f] = bt[f] - mu * sc;
}

// ---------------------------------------------------------------------------
// Fused BN+ReLU + mean-pool + FC1(relu) + FC2. One block (128 thr) per graph.
// ---------------------------------------------------------------------------
__global__ __launch_bounds__(128) void k_pool_fc(const float* __restrict__ HP,
                                                 const float* __restrict__ bnp,
                                                 const int* __restrict__ batch,
                                                 const float* __restrict__ fcw1,
                                                 const float* __restrict__ fcb1,
                                                 const float* __restrict__ fcw2,
                                                 const float* __restrict__ fcb2,
                                                 float* __restrict__ out) {
    int g = blockIdx.x;
    int t = threadIdx.x;
    int lo = 0, hi = Nn;
    while (lo < hi) { int mid = (lo + hi) >> 1; if (batch[mid] < g) lo = mid + 1; else hi = mid; }
    int start = lo;
    hi = Nn;
    while (lo < hi) { int mid = (lo + hi) >> 1; if (batch[mid] < g + 1) lo = mid + 1; else hi = mid; }
    int end = lo;

    float sc = bnp[t], sh = bnp[128 + t];
    float acc = 0.f;
    for (int i = start; i < end; ++i)
        acc += fmaxf(fmaf(HP[(size_t)i * 128 + t], sc, sh), 0.f);
    float inv = 1.0f / fmaxf((float)(end - start), 1.0f);

    __shared__ float p[128];
    __shared__ float h1[64];
    p[t] = acc * inv;
    __syncthreads();
    if (t < 64) {
        float s = fcb1[t];
        for (int k = 0; k < 128; ++k) s = fmaf(p[k], fcw1[k * 64 + t], s);
        h1[t] = fmaxf(s, 0.f);
    }
    __syncthreads();
    if (t < 64) {
        float v = h1[t] * fcw2[t];
        for (int off = 32; off > 0; off >>= 1) v += __shfl_down(v, off, 64);
        if (t == 0) out[g] = v + fcb2[0];
    }
}

// ---------------------------------------------------------------------------
extern "C" void kernel_launch(void* const* d_in, const int* in_sizes, int n_in,
                              void* d_out, int out_size, void* d_ws, size_t ws_size,
                              hipStream_t stream) {
    const float* x     = (const float*)d_in[0];
    const int*   ei    = (const int*)d_in[1];   // [2,E]: src=ei[0:E), dst=ei[E:2E)
    const int*   batch = (const int*)d_in[2];
    const float* W1  = (const float*)d_in[3];
    const float* b1  = (const float*)d_in[4];
    const float* g1  = (const float*)d_in[5];
    const float* bt1 = (const float*)d_in[6];
    const float* W2  = (const float*)d_in[7];
    const float* b2  = (const float*)d_in[8];
    const float* g2  = (const float*)d_in[9];
    const float* bt2 = (const float*)d_in[10];
    const float* W3  = (const float*)d_in[11];
    const float* b3  = (const float*)d_in[12];
    const float* g3  = (const float*)d_in[13];
    const float* bt3 = (const float*)d_in[14];
    const float* fcw1 = (const float*)d_in[15];
    const float* fcb1 = (const float*)d_in[16];
    const float* fcw2 = (const float*)d_in[17];
    const float* fcb2 = (const float*)d_in[18];
    float* out = (float*)d_out;

    // Workspace layout
    ushort16* XWb    = (ushort16*)d_ws;                    // [N*128] bf16
    float*    HP     = (float*)(XWb + (size_t)Nn * HH);    // [N*128] f32
    float*    dis    = HP + (size_t)Nn * HH;               // [N]
    unsigned* cnt    = (unsigned*)(dis + Nn);              // [N]
    int*      rowptr = (int*)(cnt + Nn);                   // [N+1]
    int*      cursor = rowptr + (Nn + 1);                  // [N+1]
    int*      bsum   = cursor + (Nn + 1);                  // [512]
    int*      csr_src = bsum + 512;                        // [E]
    float*    stats  = (float*)(csr_src + Ee);             // [3*256]
    float*    bnp    = stats + 768;                        // [3*256]

    hipMemsetAsync(cnt, 0, (size_t)Nn * sizeof(unsigned), stream);
    hipMemsetAsync(stats, 0, 768 * sizeof(float), stream);

    const int* src = ei;
    const int* dst = ei + Ee;

    k_count<<<Ee / 256, 256, 0, stream>>>(dst, cnt);
    k_dis<<<(Nn + 255) / 256, 256, 0, stream>>>(cnt, dis);
    int nblk = (Nn + 255) / 256;  // 391
    k_scan1<<<nblk, 256, 0, stream>>>(cnt, rowptr, bsum);
    k_scan2<<<1, 512, 0, stream>>>(bsum, nblk);
    k_scan3<<<nblk, 256, 0, stream>>>(rowptr, cursor, bsum);
    k_fill<<<Ee / 256, 256, 0, stream>>>(src, dst, cursor, csr_src);

    const float* Ws_[3]  = {W1, W2, W3};
    const float* bs_[3]  = {b1, b2, b3};
    const float* gs_[3]  = {g1, g2, g3};
    const float* bts_[3] = {bt1, bt2, bt3};
    const float* Xin = x;
    for (int l = 0; l < 3; ++l) {
        const float* bnp_in = (l == 0) ? nullptr : (bnp + (l - 1) * 256);
        k_gemm<<<768, 256, 0, stream>>>(Xin, Ws_[l], bs_[l], bnp_in, dis, XWb);
        k_agg<<<Nn / 4, 256, 0, stream>>>(XWb, dis, rowptr, csr_src, HP);
        k_stats<<<1024, 256, 0, stream>>>(HP, stats + l * 256);
        k_bnfinal<<<1, 128, 0, stream>>>(stats + l * 256, gs_[l], bts_[l], bnp + l * 256);
        Xin = HP;  // next gemm applies BN+ReLU on load
    }
    k_pool_fc<<<Gg, 128, 0, stream>>>(HP, bnp + 512, batch, fcw1, fcb1, fcw2, fcb2, out);
}